// Round 10
// baseline (30.884 us; speedup 1.0000x reference)
//
#include <hip/hip_runtime.h>
#include <math.h>

#define NB 32
#define KK 2
#define PP 256
#define NCLOUD 8192
#define NNODES 512   // K*P
#define NCOEF 163840 // B*K*P*COEF_D
#define SURF0 257
#define NCHUNK 32                 // chunks per batch (256 pts each)
#define NSURF (NB * NCHUNK)       // 1024
#define NBLK (SURF0 + NSURF)      // 1281

// ws float slot layout (all written every call; no memset of ws needed):
//   [0,128)   sep per chamfer half-block
//   [128,192) cov per (b,k)
//   [192,256) reg per block
//   [256,258) joint cosv/locv sums
//   [288, 288+128*512)   pchf: per chamfer half-block {fwd[256] | bwd[256]} min-d2
//   [65824, 65824+32*32*512) partial surf min-g per (b,chunk,node)
#define SL_SEP 0
#define SL_COV 128
#define SL_REG 192
#define SL_JNT 256
#define PCHF 288
#define PART0 65824

__device__ inline float waveSum(float v) {
#pragma unroll
  for (int o = 32; o > 0; o >>= 1) v += __shfl_down(v, o);
  return v;
}
__device__ inline float waveMax(float v) {
#pragma unroll
  for (int o = 32; o > 0; o >>= 1) v = fmaxf(v, __shfl_down(v, o));
  return v;
}
__device__ inline float waveMin(float v) {
#pragma unroll
  for (int o = 32; o > 0; o >>= 1) v = fminf(v, __shfl_down(v, o));
  return v;
}
__device__ inline float smooth_l1(float d) {
  d = fabsf(d);
  return d < 0.1f ? 5.0f * d * d : d - 0.05f;
}

// Grid: [0,128) chamfer+sep half-blocks: bk=bid>>1, h=bid&1, wave owns 32 j's
//       [128,192) cov per (b,k) | [192,256) reg | 256 joint
//       [257,1281) surf: s=bid-257, b=s>>5, chunk c=s&31 (256 pts);
//                  wave owns 64-pt slice, lane owns 8 nodes (lane+64q)
__global__ __launch_bounds__(256) void mega_kernel(
    const float* __restrict__ coefs,
    const float* __restrict__ preds,
    const float* __restrict__ nodes,
    const float* __restrict__ cloud,
    const int* __restrict__ cls,
    const float* __restrict__ pjl, const float* __restrict__ pja,
    const float* __restrict__ gjl, const float* __restrict__ gja,
    const float* __restrict__ gps,
    float* __restrict__ ws) {
  const int bid = blockIdx.x;
  const int t = threadIdx.x;
  const int wave = t >> 6, lane = t & 63;
  __shared__ float4 sh4[512];     // 8 KB
  __shared__ float shg[2048];     // 8 KB (cross-wave combine)
  __shared__ float red[12][4];

  if (bid < 128) {
    // ------------- chamfer + separation: (b,k) x j-half -------------
    const int bk = bid >> 1;
    const int h = bid & 1;
    const float* pb = preds + (size_t)bk * PP * 3;
    const float* nbp = nodes + (size_t)bk * PP * 3;
    {
      float x = pb[3 * t], y = pb[3 * t + 1], z = pb[3 * t + 2];
      sh4[t] = make_float4(x, y, z, x * x + y * y + z * z);         // preds
      x = nbp[3 * t]; y = nbp[3 * t + 1]; z = nbp[3 * t + 2];
      sh4[256 + t] = make_float4(x, y, z, x * x + y * y + z * z);   // nodes
    }
    __syncthreads();
    float4 ptv[4], ntv[4];
#pragma unroll
    for (int q = 0; q < 4; ++q) {
      ptv[q] = sh4[lane + q * 64];
      ntv[q] = sh4[256 + lane + q * 64];
    }
    const float s0 = gps[bk * 3 + 0], s1 = gps[bk * 3 + 1], s2 = gps[bk * 3 + 2];
    const float thr = sqrtf(s0 * s0 + s1 * s1 + s2 * s2) * 0.125f;
    float g1[4], g2[4], sep = 0.0f;
#pragma unroll
    for (int q = 0; q < 4; ++q) { g1[q] = 1e30f; g2[q] = 1e30f; }
    const int j0 = h * 128 + wave * 32;
#pragma unroll 2
    for (int jj = 0; jj < 32; ++jj) {
      const int j = j0 + jj;
      const float4 pj = sh4[j];
      const float4 nj = sh4[256 + j];
#pragma unroll
      for (int q = 0; q < 4; ++q) {
        float dot = fmaf(ptv[q].x, nj.x, fmaf(ptv[q].y, nj.y, ptv[q].z * nj.z));
        g1[q] = fminf(g1[q], fmaf(-2.0f, dot, nj.w));
        dot = fmaf(ntv[q].x, pj.x, fmaf(ntv[q].y, pj.y, ntv[q].z * pj.z));
        g2[q] = fminf(g2[q], fmaf(-2.0f, dot, pj.w));
        dot = fmaf(ntv[q].x, nj.x, fmaf(ntv[q].y, nj.y, ntv[q].z * nj.z));
        const float d2 = fmaf(-2.0f, dot, ntv[q].w + nj.w);
        const float d = sqrtf(fmaxf(d2, 0.0f));
        if (j != lane + q * 64) sep += fmaxf(thr - d, 0.0f);
      }
    }
    // cross-wave min combine; store per-element partial min-d2 (fwd/bwd)
#pragma unroll
    for (int q = 0; q < 4; ++q) {
      shg[wave * 256 + lane + q * 64] = ptv[q].w + g1[q];
      shg[1024 + wave * 256 + lane + q * 64] = ntv[q].w + g2[q];
    }
    __syncthreads();
    float* pc = ws + PCHF + (size_t)bid * 512;
    pc[t] = fminf(fminf(shg[t], shg[256 + t]),
                  fminf(shg[512 + t], shg[768 + t]));
    pc[256 + t] = fminf(fminf(shg[1024 + t], shg[1280 + t]),
                        fminf(shg[1536 + t], shg[1792 + t]));
    sep = waveSum(sep);
    if (lane == 0) red[0][wave] = sep;
    __syncthreads();
    if (t == 0)
      ws[SL_SEP + bid] = red[0][0] + red[0][1] + red[0][2] + red[0][3];

  } else if (bid < 192) {
    // ---------------- coverage per (b,k) ----------------
    const int bk = bid - 128;
    const int b = bk >> 1;
    const int k = bk & 1;
    float pmax0 = -1e9f, pmax1 = -1e9f, pmax2 = -1e9f;
    float pmin0 = 1e9f, pmin1 = 1e9f, pmin2 = 1e9f;
    const float* cb = cloud + (size_t)b * NCLOUD * 3;
    const int* lb = cls + (size_t)b * NCLOUD;
    for (int i = t; i < NCLOUD; i += 256) {
      if (lb[i] == k) {
        const float x = cb[i * 3 + 0], y = cb[i * 3 + 1], z = cb[i * 3 + 2];
        pmax0 = fmaxf(pmax0, x); pmax1 = fmaxf(pmax1, y); pmax2 = fmaxf(pmax2, z);
        pmin0 = fminf(pmin0, x); pmin1 = fminf(pmin1, y); pmin2 = fminf(pmin2, z);
      }
    }
    const float* nb = nodes + (size_t)bk * PP * 3;
    const float kx = nb[t * 3 + 0], ky = nb[t * 3 + 1], kz = nb[t * 3 + 2];
    pmax0 = waveMax(pmax0); pmax1 = waveMax(pmax1); pmax2 = waveMax(pmax2);
    pmin0 = waveMin(pmin0); pmin1 = waveMin(pmin1); pmin2 = waveMin(pmin2);
    float kmax0 = waveMax(kx), kmax1 = waveMax(ky), kmax2 = waveMax(kz);
    float kmin0 = waveMin(kx), kmin1 = waveMin(ky), kmin2 = waveMin(kz);
    if (lane == 0) {
      red[0][wave] = pmax0; red[1][wave] = pmax1; red[2][wave] = pmax2;
      red[3][wave] = pmin0; red[4][wave] = pmin1; red[5][wave] = pmin2;
      red[6][wave] = kmax0; red[7][wave] = kmax1; red[8][wave] = kmax2;
      red[9][wave] = kmin0; red[10][wave] = kmin1; red[11][wave] = kmin2;
    }
    __syncthreads();
    if (t == 0) {
      float v[12];
#pragma unroll
      for (int q = 0; q < 12; ++q) {
        if (q < 3 || (q >= 6 && q < 9))
          v[q] = fmaxf(fmaxf(red[q][0], red[q][1]), fmaxf(red[q][2], red[q][3]));
        else
          v[q] = fminf(fminf(red[q][0], red[q][1]), fminf(red[q][2], red[q][3]));
      }
      float s = 0.0f;
#pragma unroll
      for (int c2 = 0; c2 < 3; ++c2)
        s += 0.5f * (smooth_l1(v[6 + c2] - v[0 + c2]) + smooth_l1(v[9 + c2] - v[3 + c2]));
      ws[SL_COV + bk] = s;
    }

  } else if (bid < 256) {
    // ---------------- regularizer ----------------
    const int r = bid - 192;
    const float4* c4 = (const float4*)coefs;
    float v = 0.0f;
    for (int i = r * 256 + t; i < NCOEF / 4; i += 64 * 256) {
      const float4 q = c4[i];
      v += q.x * q.x + q.y * q.y + q.z * q.z + q.w * q.w;
    }
    v = waveSum(v);
    if (lane == 0) red[0][wave] = v;
    __syncthreads();
    if (t == 0)
      ws[SL_REG + r] = red[0][0] + red[0][1] + red[0][2] + red[0][3];

  } else if (bid == 256) {
    // ---------------- joint ----------------
    float cosv = 0.0f, locv = 0.0f;
    if (t < NB) {
      const float axj = pja[t * 3 + 0], ayj = pja[t * 3 + 1], azj = pja[t * 3 + 2];
      const float gx = gja[t * 3 + 0], gy = gja[t * 3 + 1], gz = gja[t * 3 + 2];
      const float dot = axj * gx + ayj * gy + azj * gz;
      const float na = sqrtf(axj * axj + ayj * ayj + azj * azj);
      const float nbn = sqrtf(gx * gx + gy * gy + gz * gz);
      cosv = dot / fmaxf(na * nbn, 1e-8f);
      const float ux = gx / nbn, uy = gy / nbn, uz = gz / nbn;
      const float px = gjl[t * 3 + 0], py = gjl[t * 3 + 1], pz = gjl[t * 3 + 2];
      const float qx = px + ux, qy = py + uy, qz = pz + uz;
      const float rx = pjl[t * 3 + 0], ry = pjl[t * 3 + 1], rz = pjl[t * 3 + 2];
      const float xx = px - qx, xy = py - qy, xz = pz - qz;
      const float tnum = (rx - qx) * xx + (ry - qy) * xy + (rz - qz) * xz;
      const float tden = xx * xx + xy * xy + xz * xz;
      const float tv = tnum / tden;
      const float vx = tv * xx + (qx - rx);
      const float vy = tv * xy + (qy - ry);
      const float vz = tv * xz + (qz - rz);
      locv = sqrtf(vx * vx + vy * vy + vz * vz);
    }
    cosv = waveSum(cosv);
    locv = waveSum(locv);
    if (t == 0) { ws[SL_JNT + 0] = cosv; ws[SL_JNT + 1] = locv; }

  } else {
    // ---------------- surf partial: (b, 256-pt chunk) ----------------
    const int s = bid - SURF0;
    const int b = s >> 5;
    const int c = s & 31;
    const float* cb = cloud + ((size_t)b * NCLOUD + (size_t)c * 256) * 3;
    {
      const float qx = cb[3 * t], qy = cb[3 * t + 1], qz = cb[3 * t + 2];
      sh4[t] = make_float4(qx, qy, qz, 0.5f * (qx * qx + qy * qy + qz * qz));
    }
    __syncthreads();
    const float* nb = nodes + (size_t)b * NNODES * 3;
    float nxv[8], nyv[8], nzv[8], mg[8];
#pragma unroll
    for (int q = 0; q < 8; ++q) {
      const int n = lane + q * 64;
      nxv[q] = nb[3 * n]; nyv[q] = nb[3 * n + 1]; nzv[q] = nb[3 * n + 2];
      mg[q] = 1e30f;
    }
    const int p0 = wave * 64;
#pragma unroll 4
    for (int j = 0; j < 64; ++j) {
      const float4 q4 = sh4[p0 + j];
#pragma unroll
      for (int q = 0; q < 8; ++q)
        mg[q] = fminf(mg[q],
                      fmaf(-nxv[q], q4.x,
                           fmaf(-nyv[q], q4.y, fmaf(-nzv[q], q4.z, q4.w))));
    }
    // cross-wave min combine in LDS, coalesced store of min-g
#pragma unroll
    for (int q = 0; q < 8; ++q)
      shg[wave * 512 + lane + q * 64] = mg[q];
    __syncthreads();
    float* pout = ws + PART0 + ((size_t)b * NCHUNK + c) * NNODES;
#pragma unroll
    for (int g = 0; g < 2; ++g) {
      const int node = g * 256 + t;
      pout[node] = fminf(fminf(shg[node], shg[512 + node]),
                         fminf(shg[1024 + node], shg[1536 + node]));
    }
  }
}

// ------- final1: per-batch surf + chamfer combine + weighted add to out -------
__global__ __launch_bounds__(256) void final1_kernel(
    const float* __restrict__ nodes, const float* __restrict__ ws,
    float* __restrict__ out) {
  const int b = blockIdx.x;
  const int t = threadIdx.x;
  const int wave = t >> 6, lane = t & 63;
  // surf: min-g over 32 chunks, then sqrt(2g + |n|^2)
  const float* partial = ws + PART0;
  const float* nb = nodes + (size_t)b * NNODES * 3;
  float ssum = 0.0f;
#pragma unroll
  for (int g = 0; g < 2; ++g) {
    const int node = g * 256 + t;
    float m = 1e30f;
#pragma unroll
    for (int c = 0; c < NCHUNK; ++c)
      m = fminf(m, partial[((size_t)b * NCHUNK + c) * NNODES + node]);
    const float x = nb[3 * node], y = nb[3 * node + 1], z = nb[3 * node + 2];
    const float nn = x * x + y * y + z * z;
    ssum += sqrtf(fmaxf(fmaf(2.0f, m, nn), 1e-12f));
  }
  // chamfer: min over the 2 j-halves, element t of each (b,k)
  float csum = 0.0f;
#pragma unroll
  for (int k = 0; k < KK; ++k) {
    const int bk = b * KK + k;
    const float* h0 = ws + PCHF + (size_t)(2 * bk) * 512;
    const float* h1 = ws + PCHF + (size_t)(2 * bk + 1) * 512;
    const float fwd = fminf(h0[t], h1[t]);
    const float bwd = fminf(h0[256 + t], h1[256 + t]);
    csum += sqrtf(fmaxf(fwd, 1e-12f)) + sqrtf(fmaxf(bwd, 1e-12f));
  }
  ssum = waveSum(ssum);
  csum = waveSum(csum);
  __shared__ float r[2][4];
  if (lane == 0) { r[0][wave] = ssum; r[1][wave] = csum; }
  __syncthreads();
  if (t == 0) {
    const float ssum_t = r[0][0] + r[0][1] + r[0][2] + r[0][3];
    const float csum_t = r[1][0] + r[1][1] + r[1][2] + r[1][3];
    float v = ssum_t * (5.0f / (float)(NB * NNODES)) +
              csum_t * (1.0f / (float)(KK * NB * PP));
    v += (ws[SL_COV + 2 * b] + ws[SL_COV + 2 * b + 1]) *
         (1.0f / (float)(NB * KK * 3));
    v += (ws[SL_REG + 2 * b] + ws[SL_REG + 2 * b + 1]) * (0.01f / (float)NCOEF);
    v += (ws[SL_SEP + 4 * b] + ws[SL_SEP + 4 * b + 1] + ws[SL_SEP + 4 * b + 2] +
          ws[SL_SEP + 4 * b + 3]) *
         (2.0f / (float)(NB * KK * PP * (PP - 1)));
    if (b == 0) {
      const float axis = 1.0f - ws[SL_JNT + 0] / (float)NB;
      const float loc = ws[SL_JNT + 1] / (float)NB;
      v += loc + 0.5f * axis;
    }
    atomicAdd(out, v);
  }
}

extern "C" void kernel_launch(void* const* d_in, const int* in_sizes, int n_in,
                              void* d_out, int out_size, void* d_ws, size_t ws_size,
                              hipStream_t stream) {
  const float* coefs = (const float*)d_in[0];
  const float* preds = (const float*)d_in[1];
  const float* nodes = (const float*)d_in[2];
  const float* cloud = (const float*)d_in[3];
  const int* cls = (const int*)d_in[4];
  const float* pjl = (const float*)d_in[5];
  const float* pja = (const float*)d_in[6];
  const float* gjl = (const float*)d_in[7];
  const float* gja = (const float*)d_in[8];
  const float* gps = (const float*)d_in[9];
  float* out = (float*)d_out;
  float* ws = (float*)d_ws;

  hipMemsetAsync(out, 0, sizeof(float), stream);  // accumulator for final1
  mega_kernel<<<NBLK, 256, 0, stream>>>(coefs, preds, nodes, cloud, cls,
                                        pjl, pja, gjl, gja, gps, ws);
  final1_kernel<<<NB, 256, 0, stream>>>(nodes, ws, out);
}

// Round 11
// 26.062 us; speedup vs baseline: 1.1850x; 1.1850x over previous
//
#include <hip/hip_runtime.h>
#include <math.h>

#define NB 32
#define KK 2
#define PP 256
#define NCLOUD 8192
#define NNODES 512   // K*P
#define NCOEF 163840 // B*K*P*COEF_D
#define SURF0 385
#define NCHUNK 16                 // surf chunks per batch (512 pts each)
#define NSURF (NB * NCHUNK)       // 512
#define NBLK (SURF0 + NSURF)      // 897

// ws float slot layout (all written every call; no memset, no atomics):
//   [0,256)   sep per chamfer quarter-block
//   [256,320) cov per (b,k)
//   [320,384) reg per block
//   [384,386) joint cosv/locv
//   [386,418) SB per-batch surf sqrt-sum (final1)
//   [418,450) CB per-batch chamfer sqrt-sum (final1)
//   [512, 512+256*512)      pchf: per quarter-block {fwd[256]|bwd[256]} min-d2
//   [131584, 131584+262144) partial surf min-g per (b,chunk,node)
#define SL_SEP 0
#define SL_COV 256
#define SL_REG 320
#define SL_JNT 384
#define SL_SB 386
#define SL_CB 418
#define PCHF 512
#define PART0 131584

__device__ inline float waveSum(float v) {
#pragma unroll
  for (int o = 32; o > 0; o >>= 1) v += __shfl_down(v, o);
  return v;
}
__device__ inline float waveMax(float v) {
#pragma unroll
  for (int o = 32; o > 0; o >>= 1) v = fmaxf(v, __shfl_down(v, o));
  return v;
}
__device__ inline float waveMin(float v) {
#pragma unroll
  for (int o = 32; o > 0; o >>= 1) v = fminf(v, __shfl_down(v, o));
  return v;
}
__device__ inline float smooth_l1(float d) {
  d = fabsf(d);
  return d < 0.1f ? 5.0f * d * d : d - 0.05f;
}

// Grid: [0,256) chamfer quarters: bk=bid>>2, h=bid&3, wave owns 16 j's
//       [256,320) cov | [320,384) reg | 384 joint
//       [385,897) surf: s=bid-385, b=s>>4, chunk c=s&15 (512 pts);
//                 wave owns 128-pt slice, lane owns 8 nodes (lane+64q)
__global__ __launch_bounds__(256) void mega_kernel(
    const float* __restrict__ coefs,
    const float* __restrict__ preds,
    const float* __restrict__ nodes,
    const float* __restrict__ cloud,
    const int* __restrict__ cls,
    const float* __restrict__ pjl, const float* __restrict__ pja,
    const float* __restrict__ gjl, const float* __restrict__ gja,
    const float* __restrict__ gps,
    float* __restrict__ ws) {
  const int bid = blockIdx.x;
  const int t = threadIdx.x;
  const int wave = t >> 6, lane = t & 63;
  __shared__ float4 sh4[512];     // 8 KB
  __shared__ float shg[2048];     // 8 KB (cross-wave combine)
  __shared__ float red[12][4];

  if (bid < 256) {
    // -------- chamfer + separation: (b,k) x j-quarter (wave: 16 j's) --------
    const int bk = bid >> 2;
    const int h = bid & 3;
    const float* pb = preds + (size_t)bk * PP * 3;
    const float* nbp = nodes + (size_t)bk * PP * 3;
    {
      float x = pb[3 * t], y = pb[3 * t + 1], z = pb[3 * t + 2];
      sh4[t] = make_float4(x, y, z, x * x + y * y + z * z);         // preds
      x = nbp[3 * t]; y = nbp[3 * t + 1]; z = nbp[3 * t + 2];
      sh4[256 + t] = make_float4(x, y, z, x * x + y * y + z * z);   // nodes
    }
    __syncthreads();
    float4 ptv[4], ntv[4];
#pragma unroll
    for (int q = 0; q < 4; ++q) {
      ptv[q] = sh4[lane + q * 64];
      ntv[q] = sh4[256 + lane + q * 64];
    }
    const float s0 = gps[bk * 3 + 0], s1 = gps[bk * 3 + 1], s2 = gps[bk * 3 + 2];
    const float thr = sqrtf(s0 * s0 + s1 * s1 + s2 * s2) * 0.125f;
    float g1[4], g2[4], sep = 0.0f;
#pragma unroll
    for (int q = 0; q < 4; ++q) { g1[q] = 1e30f; g2[q] = 1e30f; }
    const int j0 = h * 64 + wave * 16;
#pragma unroll 4
    for (int jj = 0; jj < 16; ++jj) {
      const int j = j0 + jj;
      const float4 pj = sh4[j];
      const float4 nj = sh4[256 + j];
#pragma unroll
      for (int q = 0; q < 4; ++q) {
        float dot = fmaf(ptv[q].x, nj.x, fmaf(ptv[q].y, nj.y, ptv[q].z * nj.z));
        g1[q] = fminf(g1[q], fmaf(-2.0f, dot, nj.w));
        dot = fmaf(ntv[q].x, pj.x, fmaf(ntv[q].y, pj.y, ntv[q].z * pj.z));
        g2[q] = fminf(g2[q], fmaf(-2.0f, dot, pj.w));
        dot = fmaf(ntv[q].x, nj.x, fmaf(ntv[q].y, nj.y, ntv[q].z * nj.z));
        const float d2 = fmaf(-2.0f, dot, ntv[q].w + nj.w);
        const float d = sqrtf(fmaxf(d2, 0.0f));
        if (j != lane + q * 64) sep += fmaxf(thr - d, 0.0f);
      }
    }
    // cross-wave min combine; store per-element partial min-d2 (fwd/bwd)
#pragma unroll
    for (int q = 0; q < 4; ++q) {
      shg[wave * 256 + lane + q * 64] = ptv[q].w + g1[q];
      shg[1024 + wave * 256 + lane + q * 64] = ntv[q].w + g2[q];
    }
    __syncthreads();
    float* pc = ws + PCHF + (size_t)bid * 512;
    pc[t] = fminf(fminf(shg[t], shg[256 + t]),
                  fminf(shg[512 + t], shg[768 + t]));
    pc[256 + t] = fminf(fminf(shg[1024 + t], shg[1280 + t]),
                        fminf(shg[1536 + t], shg[1792 + t]));
    sep = waveSum(sep);
    if (lane == 0) red[0][wave] = sep;
    __syncthreads();
    if (t == 0)
      ws[SL_SEP + bid] = red[0][0] + red[0][1] + red[0][2] + red[0][3];

  } else if (bid < 320) {
    // ---------------- coverage per (b,k) ----------------
    const int bk = bid - 256;
    const int b = bk >> 1;
    const int k = bk & 1;
    float pmax0 = -1e9f, pmax1 = -1e9f, pmax2 = -1e9f;
    float pmin0 = 1e9f, pmin1 = 1e9f, pmin2 = 1e9f;
    const float* cb = cloud + (size_t)b * NCLOUD * 3;
    const int* lb = cls + (size_t)b * NCLOUD;
    for (int i = t; i < NCLOUD; i += 256) {
      if (lb[i] == k) {
        const float x = cb[i * 3 + 0], y = cb[i * 3 + 1], z = cb[i * 3 + 2];
        pmax0 = fmaxf(pmax0, x); pmax1 = fmaxf(pmax1, y); pmax2 = fmaxf(pmax2, z);
        pmin0 = fminf(pmin0, x); pmin1 = fminf(pmin1, y); pmin2 = fminf(pmin2, z);
      }
    }
    const float* nb = nodes + (size_t)bk * PP * 3;
    const float kx = nb[t * 3 + 0], ky = nb[t * 3 + 1], kz = nb[t * 3 + 2];
    pmax0 = waveMax(pmax0); pmax1 = waveMax(pmax1); pmax2 = waveMax(pmax2);
    pmin0 = waveMin(pmin0); pmin1 = waveMin(pmin1); pmin2 = waveMin(pmin2);
    float kmax0 = waveMax(kx), kmax1 = waveMax(ky), kmax2 = waveMax(kz);
    float kmin0 = waveMin(kx), kmin1 = waveMin(ky), kmin2 = waveMin(kz);
    if (lane == 0) {
      red[0][wave] = pmax0; red[1][wave] = pmax1; red[2][wave] = pmax2;
      red[3][wave] = pmin0; red[4][wave] = pmin1; red[5][wave] = pmin2;
      red[6][wave] = kmax0; red[7][wave] = kmax1; red[8][wave] = kmax2;
      red[9][wave] = kmin0; red[10][wave] = kmin1; red[11][wave] = kmin2;
    }
    __syncthreads();
    if (t == 0) {
      float v[12];
#pragma unroll
      for (int q = 0; q < 12; ++q) {
        if (q < 3 || (q >= 6 && q < 9))
          v[q] = fmaxf(fmaxf(red[q][0], red[q][1]), fmaxf(red[q][2], red[q][3]));
        else
          v[q] = fminf(fminf(red[q][0], red[q][1]), fminf(red[q][2], red[q][3]));
      }
      float s = 0.0f;
#pragma unroll
      for (int c2 = 0; c2 < 3; ++c2)
        s += 0.5f * (smooth_l1(v[6 + c2] - v[0 + c2]) + smooth_l1(v[9 + c2] - v[3 + c2]));
      ws[SL_COV + bk] = s;
    }

  } else if (bid < 384) {
    // ---------------- regularizer ----------------
    const int r = bid - 320;
    const float4* c4 = (const float4*)coefs;
    float v = 0.0f;
    for (int i = r * 256 + t; i < NCOEF / 4; i += 64 * 256) {
      const float4 q = c4[i];
      v += q.x * q.x + q.y * q.y + q.z * q.z + q.w * q.w;
    }
    v = waveSum(v);
    if (lane == 0) red[0][wave] = v;
    __syncthreads();
    if (t == 0)
      ws[SL_REG + r] = red[0][0] + red[0][1] + red[0][2] + red[0][3];

  } else if (bid == 384) {
    // ---------------- joint ----------------
    float cosv = 0.0f, locv = 0.0f;
    if (t < NB) {
      const float axj = pja[t * 3 + 0], ayj = pja[t * 3 + 1], azj = pja[t * 3 + 2];
      const float gx = gja[t * 3 + 0], gy = gja[t * 3 + 1], gz = gja[t * 3 + 2];
      const float dot = axj * gx + ayj * gy + azj * gz;
      const float na = sqrtf(axj * axj + ayj * ayj + azj * azj);
      const float nbn = sqrtf(gx * gx + gy * gy + gz * gz);
      cosv = dot / fmaxf(na * nbn, 1e-8f);
      const float ux = gx / nbn, uy = gy / nbn, uz = gz / nbn;
      const float px = gjl[t * 3 + 0], py = gjl[t * 3 + 1], pz = gjl[t * 3 + 2];
      const float qx = px + ux, qy = py + uy, qz = pz + uz;
      const float rx = pjl[t * 3 + 0], ry = pjl[t * 3 + 1], rz = pjl[t * 3 + 2];
      const float xx = px - qx, xy = py - qy, xz = pz - qz;
      const float tnum = (rx - qx) * xx + (ry - qy) * xy + (rz - qz) * xz;
      const float tden = xx * xx + xy * xy + xz * xz;
      const float tv = tnum / tden;
      const float vx = tv * xx + (qx - rx);
      const float vy = tv * xy + (qy - ry);
      const float vz = tv * xz + (qz - rz);
      locv = sqrtf(vx * vx + vy * vy + vz * vz);
    }
    cosv = waveSum(cosv);
    locv = waveSum(locv);
    if (t == 0) { ws[SL_JNT + 0] = cosv; ws[SL_JNT + 1] = locv; }

  } else {
    // ---------------- surf partial: (b, 512-pt chunk) ----------------
    const int s = bid - SURF0;
    const int b = s >> 4;
    const int c = s & 15;
    const float* cb = cloud + ((size_t)b * NCLOUD + (size_t)c * 512) * 3;
#pragma unroll
    for (int g = 0; g < 2; ++g) {
      const int idx = g * 256 + t;
      const float qx = cb[3 * idx], qy = cb[3 * idx + 1], qz = cb[3 * idx + 2];
      sh4[idx] = make_float4(qx, qy, qz, 0.5f * (qx * qx + qy * qy + qz * qz));
    }
    __syncthreads();
    const float* nb = nodes + (size_t)b * NNODES * 3;
    float nxv[8], nyv[8], nzv[8], mg[8];
#pragma unroll
    for (int q = 0; q < 8; ++q) {
      const int n = lane + q * 64;
      nxv[q] = nb[3 * n]; nyv[q] = nb[3 * n + 1]; nzv[q] = nb[3 * n + 2];
      mg[q] = 1e30f;
    }
    const int p0 = wave * 128;
#pragma unroll 4
    for (int j = 0; j < 128; ++j) {
      const float4 q4 = sh4[p0 + j];
#pragma unroll
      for (int q = 0; q < 8; ++q)
        mg[q] = fminf(mg[q],
                      fmaf(-nxv[q], q4.x,
                           fmaf(-nyv[q], q4.y, fmaf(-nzv[q], q4.z, q4.w))));
    }
    // cross-wave min combine in LDS, coalesced store of min-g
#pragma unroll
    for (int q = 0; q < 8; ++q)
      shg[wave * 512 + lane + q * 64] = mg[q];
    __syncthreads();
    float* pout = ws + PART0 + ((size_t)b * NCHUNK + c) * NNODES;
#pragma unroll
    for (int g = 0; g < 2; ++g) {
      const int node = g * 256 + t;
      pout[node] = fminf(fminf(shg[node], shg[512 + node]),
                         fminf(shg[1024 + node], shg[1536 + node]));
    }
  }
}

// ------- final1: per-batch surf min over chunks + chamfer min over quarters -------
__global__ __launch_bounds__(256) void final1_kernel(
    const float* __restrict__ nodes, float* __restrict__ ws) {
  const int b = blockIdx.x;
  const int t = threadIdx.x;
  const int wave = t >> 6, lane = t & 63;
  const float* partial = ws + PART0;
  const float* nb = nodes + (size_t)b * NNODES * 3;
  float ssum = 0.0f;
#pragma unroll
  for (int g = 0; g < 2; ++g) {
    const int node = g * 256 + t;
    float m = 1e30f;
#pragma unroll
    for (int c = 0; c < NCHUNK; ++c)
      m = fminf(m, partial[((size_t)b * NCHUNK + c) * NNODES + node]);
    const float x = nb[3 * node], y = nb[3 * node + 1], z = nb[3 * node + 2];
    const float nn = x * x + y * y + z * z;
    ssum += sqrtf(fmaxf(fmaf(2.0f, m, nn), 1e-12f));
  }
  float csum = 0.0f;
#pragma unroll
  for (int k = 0; k < KK; ++k) {
    const int bk = b * KK + k;
    const float* q0 = ws + PCHF + (size_t)(4 * bk + 0) * 512;
    const float* q1 = ws + PCHF + (size_t)(4 * bk + 1) * 512;
    const float* q2 = ws + PCHF + (size_t)(4 * bk + 2) * 512;
    const float* q3 = ws + PCHF + (size_t)(4 * bk + 3) * 512;
    const float fwd = fminf(fminf(q0[t], q1[t]), fminf(q2[t], q3[t]));
    const float bwd = fminf(fminf(q0[256 + t], q1[256 + t]),
                            fminf(q2[256 + t], q3[256 + t]));
    csum += sqrtf(fmaxf(fwd, 1e-12f)) + sqrtf(fmaxf(bwd, 1e-12f));
  }
  ssum = waveSum(ssum);
  csum = waveSum(csum);
  __shared__ float r[2][4];
  if (lane == 0) { r[0][wave] = ssum; r[1][wave] = csum; }
  __syncthreads();
  if (t == 0) {
    ws[SL_SB + b] = r[0][0] + r[0][1] + r[0][2] + r[0][3];
    ws[SL_CB + b] = r[1][0] + r[1][1] + r[1][2] + r[1][3];
  }
}

// ---------------- final2: one wave sums all slots ----------------
__global__ __launch_bounds__(64) void final2_kernel(
    const float* __restrict__ ws, float* __restrict__ out) {
  const int t = threadIdx.x;
  float sep_s = ws[SL_SEP + t] + ws[SL_SEP + 64 + t] + ws[SL_SEP + 128 + t] +
                ws[SL_SEP + 192 + t];
  float cov_s = ws[SL_COV + t];
  float reg_s = ws[SL_REG + t];
  float srf_s = (t < NB) ? ws[SL_SB + t] : 0.0f;
  float chf_s = (t < NB) ? ws[SL_CB + t] : 0.0f;
  sep_s = waveSum(sep_s);
  cov_s = waveSum(cov_s);
  reg_s = waveSum(reg_s);
  srf_s = waveSum(srf_s);
  chf_s = waveSum(chf_s);
  if (t == 0) {
    const float chf = chf_s / (float)(KK * NB * PP);
    const float sep = sep_s / (float)(NB * KK * PP * (PP - 1));
    const float surf = srf_s / (float)(NB * NNODES);
    const float cov = cov_s / (float)(NB * KK * 3);
    const float axis = 1.0f - ws[SL_JNT + 0] / (float)NB;
    const float loc = ws[SL_JNT + 1] / (float)NB;
    const float reg = reg_s / (float)NCOEF;
    out[0] = chf + cov + surf * 5.0f + (loc + 0.5f * axis) + reg * 0.01f + sep * 2.0f;
  }
}

extern "C" void kernel_launch(void* const* d_in, const int* in_sizes, int n_in,
                              void* d_out, int out_size, void* d_ws, size_t ws_size,
                              hipStream_t stream) {
  const float* coefs = (const float*)d_in[0];
  const float* preds = (const float*)d_in[1];
  const float* nodes = (const float*)d_in[2];
  const float* cloud = (const float*)d_in[3];
  const int* cls = (const int*)d_in[4];
  const float* pjl = (const float*)d_in[5];
  const float* pja = (const float*)d_in[6];
  const float* gjl = (const float*)d_in[7];
  const float* gja = (const float*)d_in[8];
  const float* gps = (const float*)d_in[9];
  float* out = (float*)d_out;
  float* ws = (float*)d_ws;

  mega_kernel<<<NBLK, 256, 0, stream>>>(coefs, preds, nodes, cloud, cls,
                                        pjl, pja, gjl, gja, gps, ws);
  final1_kernel<<<NB, 256, 0, stream>>>(nodes, ws);
  final2_kernel<<<1, 64, 0, stream>>>(ws, out);
}

// Round 12
// 24.880 us; speedup vs baseline: 1.2413x; 1.0475x over previous
//
#include <hip/hip_runtime.h>
#include <math.h>

#define NB 32
#define KK 2
#define PP 256
#define NCLOUD 8192
#define NNODES 512   // K*P
#define NCOEF 163840 // B*K*P*COEF_D
#define SURF0 385
#define NCHUNK 16                 // surf chunks per batch (512 pts each)
#define NSURF (NB * NCHUNK)       // 512
#define NBLK (SURF0 + NSURF)      // 897

// ws float slot layout (all written every call; no memset, no ws atomics):
//   [0,256)   sep per chamfer quarter-block (8 per batch)
//   [256,320) cov per (b,k)          (2 per batch)
//   [320,384) reg per block          (2 per batch share)
//   [384,386) joint cosv/locv
//   [512, 512+256*512)      pchf: per quarter-block {fwd[256]|bwd[256]} min-d2
//   [131584, 131584+262144) partial surf min-g per (b,chunk,node)
#define SL_SEP 0
#define SL_COV 256
#define SL_REG 320
#define SL_JNT 384
#define PCHF 512
#define PART0 131584

__device__ inline float waveSum(float v) {
#pragma unroll
  for (int o = 32; o > 0; o >>= 1) v += __shfl_down(v, o);
  return v;
}
__device__ inline float waveMax(float v) {
#pragma unroll
  for (int o = 32; o > 0; o >>= 1) v = fmaxf(v, __shfl_down(v, o));
  return v;
}
__device__ inline float waveMin(float v) {
#pragma unroll
  for (int o = 32; o > 0; o >>= 1) v = fminf(v, __shfl_down(v, o));
  return v;
}
__device__ inline float smooth_l1(float d) {
  d = fabsf(d);
  return d < 0.1f ? 5.0f * d * d : d - 0.05f;
}

// Grid: [0,256) chamfer quarters: bk=bid>>2, h=bid&3, wave owns 16 j's
//       [256,320) cov | [320,384) reg | 384 joint (also zeroes out[0])
//       [385,897) surf: s=bid-385, b=s>>4, chunk c=s&15 (512 pts);
//                 wave owns 128-pt slice, lane owns 8 nodes (lane+64q)
__global__ __launch_bounds__(256) void mega_kernel(
    const float* __restrict__ coefs,
    const float* __restrict__ preds,
    const float* __restrict__ nodes,
    const float* __restrict__ cloud,
    const int* __restrict__ cls,
    const float* __restrict__ pjl, const float* __restrict__ pja,
    const float* __restrict__ gjl, const float* __restrict__ gja,
    const float* __restrict__ gps,
    float* __restrict__ ws, float* __restrict__ out) {
  const int bid = blockIdx.x;
  const int t = threadIdx.x;
  const int wave = t >> 6, lane = t & 63;
  __shared__ float4 sh4[512];     // 8 KB
  __shared__ float shg[2048];     // 8 KB (cross-wave combine)
  __shared__ float red[12][4];

  if (bid < 256) {
    // -------- chamfer + separation: (b,k) x j-quarter (wave: 16 j's) --------
    const int bk = bid >> 2;
    const int h = bid & 3;
    const float* pb = preds + (size_t)bk * PP * 3;
    const float* nbp = nodes + (size_t)bk * PP * 3;
    {
      float x = pb[3 * t], y = pb[3 * t + 1], z = pb[3 * t + 2];
      sh4[t] = make_float4(x, y, z, x * x + y * y + z * z);         // preds
      x = nbp[3 * t]; y = nbp[3 * t + 1]; z = nbp[3 * t + 2];
      sh4[256 + t] = make_float4(x, y, z, x * x + y * y + z * z);   // nodes
    }
    __syncthreads();
    float4 ptv[4], ntv[4];
#pragma unroll
    for (int q = 0; q < 4; ++q) {
      ptv[q] = sh4[lane + q * 64];
      ntv[q] = sh4[256 + lane + q * 64];
    }
    const float s0 = gps[bk * 3 + 0], s1 = gps[bk * 3 + 1], s2 = gps[bk * 3 + 2];
    const float thr = sqrtf(s0 * s0 + s1 * s1 + s2 * s2) * 0.125f;
    float g1[4], g2[4], sep = 0.0f;
#pragma unroll
    for (int q = 0; q < 4; ++q) { g1[q] = 1e30f; g2[q] = 1e30f; }
    const int j0 = h * 64 + wave * 16;
#pragma unroll 4
    for (int jj = 0; jj < 16; ++jj) {
      const int j = j0 + jj;
      const float4 pj = sh4[j];
      const float4 nj = sh4[256 + j];
#pragma unroll
      for (int q = 0; q < 4; ++q) {
        float dot = fmaf(ptv[q].x, nj.x, fmaf(ptv[q].y, nj.y, ptv[q].z * nj.z));
        g1[q] = fminf(g1[q], fmaf(-2.0f, dot, nj.w));
        dot = fmaf(ntv[q].x, pj.x, fmaf(ntv[q].y, pj.y, ntv[q].z * pj.z));
        g2[q] = fminf(g2[q], fmaf(-2.0f, dot, pj.w));
        dot = fmaf(ntv[q].x, nj.x, fmaf(ntv[q].y, nj.y, ntv[q].z * nj.z));
        const float d2 = fmaf(-2.0f, dot, ntv[q].w + nj.w);
        const float d = sqrtf(fmaxf(d2, 0.0f));
        if (j != lane + q * 64) sep += fmaxf(thr - d, 0.0f);
      }
    }
    // cross-wave min combine; store per-element partial min-d2 (fwd/bwd)
#pragma unroll
    for (int q = 0; q < 4; ++q) {
      shg[wave * 256 + lane + q * 64] = ptv[q].w + g1[q];
      shg[1024 + wave * 256 + lane + q * 64] = ntv[q].w + g2[q];
    }
    __syncthreads();
    float* pc = ws + PCHF + (size_t)bid * 512;
    pc[t] = fminf(fminf(shg[t], shg[256 + t]),
                  fminf(shg[512 + t], shg[768 + t]));
    pc[256 + t] = fminf(fminf(shg[1024 + t], shg[1280 + t]),
                        fminf(shg[1536 + t], shg[1792 + t]));
    sep = waveSum(sep);
    if (lane == 0) red[0][wave] = sep;
    __syncthreads();
    if (t == 0)
      ws[SL_SEP + bid] = red[0][0] + red[0][1] + red[0][2] + red[0][3];

  } else if (bid < 320) {
    // ---------------- coverage per (b,k) ----------------
    const int bk = bid - 256;
    const int b = bk >> 1;
    const int k = bk & 1;
    float pmax0 = -1e9f, pmax1 = -1e9f, pmax2 = -1e9f;
    float pmin0 = 1e9f, pmin1 = 1e9f, pmin2 = 1e9f;
    const float* cb = cloud + (size_t)b * NCLOUD * 3;
    const int* lb = cls + (size_t)b * NCLOUD;
    for (int i = t; i < NCLOUD; i += 256) {
      if (lb[i] == k) {
        const float x = cb[i * 3 + 0], y = cb[i * 3 + 1], z = cb[i * 3 + 2];
        pmax0 = fmaxf(pmax0, x); pmax1 = fmaxf(pmax1, y); pmax2 = fmaxf(pmax2, z);
        pmin0 = fminf(pmin0, x); pmin1 = fminf(pmin1, y); pmin2 = fminf(pmin2, z);
      }
    }
    const float* nb = nodes + (size_t)bk * PP * 3;
    const float kx = nb[t * 3 + 0], ky = nb[t * 3 + 1], kz = nb[t * 3 + 2];
    pmax0 = waveMax(pmax0); pmax1 = waveMax(pmax1); pmax2 = waveMax(pmax2);
    pmin0 = waveMin(pmin0); pmin1 = waveMin(pmin1); pmin2 = waveMin(pmin2);
    float kmax0 = waveMax(kx), kmax1 = waveMax(ky), kmax2 = waveMax(kz);
    float kmin0 = waveMin(kx), kmin1 = waveMin(ky), kmin2 = waveMin(kz);
    if (lane == 0) {
      red[0][wave] = pmax0; red[1][wave] = pmax1; red[2][wave] = pmax2;
      red[3][wave] = pmin0; red[4][wave] = pmin1; red[5][wave] = pmin2;
      red[6][wave] = kmax0; red[7][wave] = kmax1; red[8][wave] = kmax2;
      red[9][wave] = kmin0; red[10][wave] = kmin1; red[11][wave] = kmin2;
    }
    __syncthreads();
    if (t == 0) {
      float v[12];
#pragma unroll
      for (int q = 0; q < 12; ++q) {
        if (q < 3 || (q >= 6 && q < 9))
          v[q] = fmaxf(fmaxf(red[q][0], red[q][1]), fmaxf(red[q][2], red[q][3]));
        else
          v[q] = fminf(fminf(red[q][0], red[q][1]), fminf(red[q][2], red[q][3]));
      }
      float s = 0.0f;
#pragma unroll
      for (int c2 = 0; c2 < 3; ++c2)
        s += 0.5f * (smooth_l1(v[6 + c2] - v[0 + c2]) + smooth_l1(v[9 + c2] - v[3 + c2]));
      ws[SL_COV + bk] = s;
    }

  } else if (bid < 384) {
    // ---------------- regularizer ----------------
    const int r = bid - 320;
    const float4* c4 = (const float4*)coefs;
    float v = 0.0f;
    for (int i = r * 256 + t; i < NCOEF / 4; i += 64 * 256) {
      const float4 q = c4[i];
      v += q.x * q.x + q.y * q.y + q.z * q.z + q.w * q.w;
    }
    v = waveSum(v);
    if (lane == 0) red[0][wave] = v;
    __syncthreads();
    if (t == 0)
      ws[SL_REG + r] = red[0][0] + red[0][1] + red[0][2] + red[0][3];

  } else if (bid == 384) {
    // ---------------- joint (+ zero the output accumulator) ----------------
    float cosv = 0.0f, locv = 0.0f;
    if (t < NB) {
      const float axj = pja[t * 3 + 0], ayj = pja[t * 3 + 1], azj = pja[t * 3 + 2];
      const float gx = gja[t * 3 + 0], gy = gja[t * 3 + 1], gz = gja[t * 3 + 2];
      const float dot = axj * gx + ayj * gy + azj * gz;
      const float na = sqrtf(axj * axj + ayj * ayj + azj * azj);
      const float nbn = sqrtf(gx * gx + gy * gy + gz * gz);
      cosv = dot / fmaxf(na * nbn, 1e-8f);
      const float ux = gx / nbn, uy = gy / nbn, uz = gz / nbn;
      const float px = gjl[t * 3 + 0], py = gjl[t * 3 + 1], pz = gjl[t * 3 + 2];
      const float qx = px + ux, qy = py + uy, qz = pz + uz;
      const float rx = pjl[t * 3 + 0], ry = pjl[t * 3 + 1], rz = pjl[t * 3 + 2];
      const float xx = px - qx, xy = py - qy, xz = pz - qz;
      const float tnum = (rx - qx) * xx + (ry - qy) * xy + (rz - qz) * xz;
      const float tden = xx * xx + xy * xy + xz * xz;
      const float tv = tnum / tden;
      const float vx = tv * xx + (qx - rx);
      const float vy = tv * xy + (qy - ry);
      const float vz = tv * xz + (qz - rz);
      locv = sqrtf(vx * vx + vy * vy + vz * vz);
    }
    cosv = waveSum(cosv);
    locv = waveSum(locv);
    if (t == 0) {
      ws[SL_JNT + 0] = cosv;
      ws[SL_JNT + 1] = locv;
      out[0] = 0.0f;   // accumulator for final1 (stream order guarantees visibility)
    }

  } else {
    // ---------------- surf partial: (b, 512-pt chunk) ----------------
    const int s = bid - SURF0;
    const int b = s >> 4;
    const int c = s & 15;
    const float* cb = cloud + ((size_t)b * NCLOUD + (size_t)c * 512) * 3;
#pragma unroll
    for (int g = 0; g < 2; ++g) {
      const int idx = g * 256 + t;
      const float qx = cb[3 * idx], qy = cb[3 * idx + 1], qz = cb[3 * idx + 2];
      sh4[idx] = make_float4(qx, qy, qz, 0.5f * (qx * qx + qy * qy + qz * qz));
    }
    __syncthreads();
    const float* nb = nodes + (size_t)b * NNODES * 3;
    float nxv[8], nyv[8], nzv[8], mg[8];
#pragma unroll
    for (int q = 0; q < 8; ++q) {
      const int n = lane + q * 64;
      nxv[q] = nb[3 * n]; nyv[q] = nb[3 * n + 1]; nzv[q] = nb[3 * n + 2];
      mg[q] = 1e30f;
    }
    const int p0 = wave * 128;
#pragma unroll 4
    for (int j = 0; j < 128; ++j) {
      const float4 q4 = sh4[p0 + j];
#pragma unroll
      for (int q = 0; q < 8; ++q)
        mg[q] = fminf(mg[q],
                      fmaf(-nxv[q], q4.x,
                           fmaf(-nyv[q], q4.y, fmaf(-nzv[q], q4.z, q4.w))));
    }
    // cross-wave min combine in LDS, coalesced store of min-g
#pragma unroll
    for (int q = 0; q < 8; ++q)
      shg[wave * 512 + lane + q * 64] = mg[q];
    __syncthreads();
    float* pout = ws + PART0 + ((size_t)b * NCHUNK + c) * NNODES;
#pragma unroll
    for (int g = 0; g < 2; ++g) {
      const int node = g * 256 + t;
      pout[node] = fminf(fminf(shg[node], shg[512 + node]),
                         fminf(shg[1024 + node], shg[1536 + node]));
    }
  }
}

// --- final1: per-batch combine (surf chunks + chamfer quarters + slot shares),
//     weighted atomicAdd into out[0] (zeroed by mega's joint block) ---
__global__ __launch_bounds__(256) void final1_kernel(
    const float* __restrict__ nodes, const float* __restrict__ ws,
    float* __restrict__ out) {
  const int b = blockIdx.x;
  const int t = threadIdx.x;
  const int wave = t >> 6, lane = t & 63;
  const float* partial = ws + PART0;
  const float* nb = nodes + (size_t)b * NNODES * 3;
  float ssum = 0.0f;
#pragma unroll
  for (int g = 0; g < 2; ++g) {
    const int node = g * 256 + t;
    float m = 1e30f;
#pragma unroll
    for (int c = 0; c < NCHUNK; ++c)
      m = fminf(m, partial[((size_t)b * NCHUNK + c) * NNODES + node]);
    const float x = nb[3 * node], y = nb[3 * node + 1], z = nb[3 * node + 2];
    const float nn = x * x + y * y + z * z;
    ssum += sqrtf(fmaxf(fmaf(2.0f, m, nn), 1e-12f));
  }
  float csum = 0.0f;
#pragma unroll
  for (int k = 0; k < KK; ++k) {
    const int bk = b * KK + k;
    const float* q0 = ws + PCHF + (size_t)(4 * bk + 0) * 512;
    const float* q1 = ws + PCHF + (size_t)(4 * bk + 1) * 512;
    const float* q2 = ws + PCHF + (size_t)(4 * bk + 2) * 512;
    const float* q3 = ws + PCHF + (size_t)(4 * bk + 3) * 512;
    const float fwd = fminf(fminf(q0[t], q1[t]), fminf(q2[t], q3[t]));
    const float bwd = fminf(fminf(q0[256 + t], q1[256 + t]),
                            fminf(q2[256 + t], q3[256 + t]));
    csum += sqrtf(fmaxf(fwd, 1e-12f)) + sqrtf(fmaxf(bwd, 1e-12f));
  }
  ssum = waveSum(ssum);
  csum = waveSum(csum);
  __shared__ float r[2][4];
  if (lane == 0) { r[0][wave] = ssum; r[1][wave] = csum; }
  __syncthreads();
  if (t == 0) {
    const float ssum_t = r[0][0] + r[0][1] + r[0][2] + r[0][3];
    const float csum_t = r[1][0] + r[1][1] + r[1][2] + r[1][3];
    float v = ssum_t * (5.0f / (float)(NB * NNODES)) +
              csum_t * (1.0f / (float)(KK * NB * PP));
    // this batch's share of sep (8 quarter slots), cov (2), reg (2)
    float sep8 = 0.0f;
#pragma unroll
    for (int q = 0; q < 8; ++q) sep8 += ws[SL_SEP + 8 * b + q];
    v += sep8 * (2.0f / (float)(NB * KK * PP * (PP - 1)));
    v += (ws[SL_COV + 2 * b] + ws[SL_COV + 2 * b + 1]) *
         (1.0f / (float)(NB * KK * 3));
    v += (ws[SL_REG + 2 * b] + ws[SL_REG + 2 * b + 1]) * (0.01f / (float)NCOEF);
    if (b == 0) {
      const float axis = 1.0f - ws[SL_JNT + 0] / (float)NB;
      const float loc = ws[SL_JNT + 1] / (float)NB;
      v += loc + 0.5f * axis;
    }
    atomicAdd(out, v);
  }
}

extern "C" void kernel_launch(void* const* d_in, const int* in_sizes, int n_in,
                              void* d_out, int out_size, void* d_ws, size_t ws_size,
                              hipStream_t stream) {
  const float* coefs = (const float*)d_in[0];
  const float* preds = (const float*)d_in[1];
  const float* nodes = (const float*)d_in[2];
  const float* cloud = (const float*)d_in[3];
  const int* cls = (const int*)d_in[4];
  const float* pjl = (const float*)d_in[5];
  const float* pja = (const float*)d_in[6];
  const float* gjl = (const float*)d_in[7];
  const float* gja = (const float*)d_in[8];
  const float* gps = (const float*)d_in[9];
  float* out = (float*)d_out;
  float* ws = (float*)d_ws;

  mega_kernel<<<NBLK, 256, 0, stream>>>(coefs, preds, nodes, cloud, cls,
                                        pjl, pja, gjl, gja, gps, ws, out);
  final1_kernel<<<NB, 256, 0, stream>>>(nodes, ws, out);
}